// Round 2
// baseline (134.906 us; speedup 1.0000x reference)
//
#include <hip/hip_runtime.h>
#include <float.h>

// CropRoi: per proposal n and channel c, crop f[b, c] to box [c0, c1) per
// axis (center/side, SCALE=4, clamped to [0,32]) and adaptive-max-pool 7x7x7.
//
// Block = dim3(7,7,7) -> i/j/k from hardware threadIdx (no integer divides).
// Grid = (C, N) -> crop bounds are wave-uniform per block.
// Input domain (side in [8,48]) gives crop length L in [2,14] -> every
// pooling segment has length 1..3, so we use a fully-unrolled 3x3x3 window
// with clamped indices (duplicate reads are idempotent under max). All 27
// loads are independent -> single memory round-trip per thread.
// Wave-uniform fallback covers out-of-domain inputs.

__global__ __launch_bounds__(343) void crop_roi_kernel(
        const float* __restrict__ f,
        const float* __restrict__ props,
        float* __restrict__ out,
        int C) {
    const int DIMS = 32;  // 128 / SCALE
    const int c = blockIdx.x;
    const int n = blockIdx.y;
    const int k = threadIdx.x;  // fastest
    const int j = threadIdx.y;
    const int i = threadIdx.z;

    const float* p = props + (size_t)n * 8;
    const int b = (int)p[0];

    // Axis bounds — float math matches JAX exactly (exact /2, /4).
    int d0 = (int)floorf((p[2] - p[5] * 0.5f) * 0.25f);
    int d1 = (int)ceilf((p[2] + p[5] * 0.5f) * 0.25f);
    int h0 = (int)floorf((p[3] - p[6] * 0.5f) * 0.25f);
    int h1 = (int)ceilf((p[3] + p[6] * 0.5f) * 0.25f);
    int w0 = (int)floorf((p[4] - p[7] * 0.5f) * 0.25f);
    int w1 = (int)ceilf((p[4] + p[7] * 0.5f) * 0.25f);
    d0 = max(d0, 0); d1 = min(d1, DIMS);
    h0 = max(h0, 0); h1 = min(h1, DIMS);
    w0 = max(w0, 0); w1 = min(w1, DIMS);
    const int Ld = d1 - d0, Lh = h1 - h0, Lw = w1 - w0;

    // Segment windows (exact integer floor/ceil divides by 7).
    const int ds = d0 + (i * Ld) / 7,  de = d0 + ((i + 1) * Ld + 6) / 7;
    const int hs = h0 + (j * Lh) / 7,  he = h0 + ((j + 1) * Lh + 6) / 7;
    const int ws = w0 + (k * Lw) / 7,  we = w0 + ((k + 1) * Lw + 6) / 7;

    const float* base = f + (((size_t)b * C + c) << 15);  // 32^3 = 32768
    float m = -FLT_MAX;  // == jnp.finfo(float32).min

    const bool fast = (Ld >= 1 && Ld <= 14 &&
                       Lh >= 1 && Lh <= 14 &&
                       Lw >= 1 && Lw <= 14);  // uniform per block
    if (fast) {
        // segment length <= 3 for L <= 14; clamp duplicates are harmless
        const int dA = ds, dB = min(ds + 1, de - 1), dC2 = min(ds + 2, de - 1);
        const int hA = hs, hB = min(hs + 1, he - 1), hC2 = min(hs + 2, he - 1);
        const int wA = ws, wB = min(ws + 1, we - 1), wC2 = min(ws + 2, we - 1);
        const int dd[3] = {dA << 10, dB << 10, dC2 << 10};
        const int hh[3] = {hA << 5,  hB << 5,  hC2 << 5};
        const int ww[3] = {wA, wB, wC2};
#pragma unroll
        for (int x = 0; x < 3; ++x) {
            const float* pd = base + dd[x];
#pragma unroll
            for (int y = 0; y < 3; ++y) {
                const float* ph = pd + hh[y];
#pragma unroll
                for (int z = 0; z < 3; ++z) {
                    m = fmaxf(m, ph[ww[z]]);
                }
            }
        }
    } else {
        for (int d = ds; d < de; ++d) {
            for (int h = hs; h < he; ++h) {
                const float* row = base + (d << 10) + (h << 5);
                for (int w = ws; w < we; ++w) m = fmaxf(m, row[w]);
            }
        }
    }

    out[((size_t)n * C + c) * 343 + (i * 49 + j * 7 + k)] = m;
}

extern "C" void kernel_launch(void* const* d_in, const int* in_sizes, int n_in,
                              void* d_out, int out_size, void* d_ws, size_t ws_size,
                              hipStream_t stream) {
    const float* f = (const float*)d_in[0];
    const float* props = (const float*)d_in[2];

    int N = in_sizes[2] / 8;       // proposals are (N, 8)
    int C = out_size / (N * 343);  // outputs are (N, C, 7, 7, 7)

    dim3 block(7, 7, 7);
    dim3 grid(C, N);
    crop_roi_kernel<<<grid, block, 0, stream>>>(f, props, (float*)d_out, C);
}

// Round 3
// 116.742 us; speedup vs baseline: 1.1556x; 1.1556x over previous
//
#include <hip/hip_runtime.h>
#include <float.h>

// CropRoi via LDS staging.
// Grid (C/2, N); block = 384 threads (6 waves); 2 channels per block (same
// proposal -> identical, block-uniform crop bounds).
// Phase 1: cooperatively load each channel's crop box (Ld*Lh*Lw <= 14^3,
//          typ ~512 floats) into LDS with linear-index coalesced global loads
//          (consecutive lanes -> consecutive w). Linear->(d,h,w) decode uses
//          __umulhi magic division (divisor block-uniform; exact for e<2^12).
// Phase 2: 686 outputs (2ch x 343) from LDS with dynamic window loops
//          (avg ~1.5 reads/axis; LDS handles the scatter cheaply).
// Fallback (never taken for harness inputs, crop side <= 14): direct global.

#define NTHREADS 384
#define MAXL 14
#define MAXV (MAXL * MAXL * MAXL)  // 2744

__global__ __launch_bounds__(NTHREADS) void crop_roi_lds(
        const float* __restrict__ f,
        const float* __restrict__ props,
        float* __restrict__ out,
        int C) {
    __shared__ float s[2 * MAXV];  // 21.95 KB
    const int cbase = blockIdx.x * 2;
    const int n = blockIdx.y;
    const int tid = threadIdx.x;

    const float* p = props + (size_t)n * 8;
    const int b = (int)p[0];

    // Bounds: float math matches JAX f32 exactly (exact *0.5, *0.25).
    int d0 = (int)floorf((p[2] - p[5] * 0.5f) * 0.25f);
    int d1 = (int)ceilf ((p[2] + p[5] * 0.5f) * 0.25f);
    int h0 = (int)floorf((p[3] - p[6] * 0.5f) * 0.25f);
    int h1 = (int)ceilf ((p[3] + p[6] * 0.5f) * 0.25f);
    int w0 = (int)floorf((p[4] - p[7] * 0.5f) * 0.25f);
    int w1 = (int)ceilf ((p[4] + p[7] * 0.5f) * 0.25f);
    d0 = max(d0, 0); d1 = min(d1, 32);
    h0 = max(h0, 0); h1 = min(h1, 32);
    w0 = max(w0, 0); w1 = min(w1, 32);
    const int Ld = d1 - d0, Lh = h1 - h0, Lw = w1 - w0;

    const float* base0 = f + (((size_t)b * C + cbase) << 15);  // 32^3
    const int nch = min(2, C - cbase);

    if (Ld <= MAXL && Lh <= MAXL && Lw <= MAXL) {
        const int D1 = Lh * Lw;        // <= 196
        const int V  = Ld * D1;        // <= 2744
        // magic reciprocals: exact floor-div for e < 2^12 (M = 2^32/D + 1)
        const unsigned Mdh = (D1 > 1) ? (unsigned)(0x100000000ULL / (unsigned)D1) + 1u : 0u;
        const unsigned Mw  = (Lw > 1) ? (unsigned)(0x100000000ULL / (unsigned)Lw) + 1u : 0u;

        for (int cs = 0; cs < nch; ++cs) {
            const float* basec = base0 + ((size_t)cs << 15);
            float* sc = s + cs * MAXV;
            for (int e = tid; e < V; e += NTHREADS) {
                unsigned d = (D1 > 1) ? __umulhi((unsigned)e, Mdh) : (unsigned)e;
                unsigned r = (unsigned)e - d * (unsigned)D1;
                unsigned h = (Lw > 1) ? __umulhi(r, Mw) : r;
                unsigned w = r - h * (unsigned)Lw;
                sc[e] = basec[(((d0 + (int)d) << 5) + (h0 + (int)h) << 5) + w0 + (int)w];
            }
        }
        __syncthreads();

        for (int t = tid; t < 343 * nch; t += NTHREADS) {
            const int cs = (t >= 343);
            const int o  = t - (cs ? 343 : 0);
            const int i = o / 49;          // const divides -> cheap magic
            const int j = (o / 7) % 7;
            const int k = o % 7;
            const int a0 = (i * Ld) / 7,  a1 = ((i + 1) * Ld + 6) / 7;
            const int b0 = (j * Lh) / 7,  b1 = ((j + 1) * Lh + 6) / 7;
            const int g0 = (k * Lw) / 7,  g1 = ((k + 1) * Lw + 6) / 7;
            float m = -FLT_MAX;  // == jnp.finfo(float32).min
            const float* sc = s + cs * MAXV;
            for (int d = a0; d < a1; ++d) {
                for (int h = b0; h < b1; ++h) {
                    const float* row = sc + (d * Lh + h) * Lw;
                    for (int w = g0; w < g1; ++w) m = fmaxf(m, row[w]);
                }
            }
            out[((size_t)n * C + cbase + cs) * 343 + o] = m;
        }
    } else {
        // Robust fallback: direct from global (not taken for harness inputs).
        for (int t = tid; t < 343 * nch; t += NTHREADS) {
            const int cs = (t >= 343);
            const int o  = t - (cs ? 343 : 0);
            const int i = o / 49, j = (o / 7) % 7, k = o % 7;
            const int ds = d0 + (i * Ld) / 7, de = d0 + ((i + 1) * Ld + 6) / 7;
            const int hs = h0 + (j * Lh) / 7, he = h0 + ((j + 1) * Lh + 6) / 7;
            const int ws = w0 + (k * Lw) / 7, we = w0 + ((k + 1) * Lw + 6) / 7;
            float m = -FLT_MAX;
            const float* basec = base0 + ((size_t)cs << 15);
            for (int d = ds; d < de; ++d) {
                for (int h = hs; h < he; ++h) {
                    const float* row = basec + (d << 10) + (h << 5);
                    for (int w = ws; w < we; ++w) m = fmaxf(m, row[w]);
                }
            }
            out[((size_t)n * C + cbase + cs) * 343 + o] = m;
        }
    }
}

extern "C" void kernel_launch(void* const* d_in, const int* in_sizes, int n_in,
                              void* d_out, int out_size, void* d_ws, size_t ws_size,
                              hipStream_t stream) {
    const float* f = (const float*)d_in[0];
    const float* props = (const float*)d_in[2];

    int N = in_sizes[2] / 8;       // proposals are (N, 8)
    int C = out_size / (N * 343);  // outputs are (N, C, 7, 7, 7)

    dim3 block(NTHREADS);
    dim3 grid((C + 1) / 2, N);
    crop_roi_lds<<<grid, block, 0, stream>>>(f, props, (float*)d_out, C);
}

// Round 4
// 113.381 us; speedup vs baseline: 1.1898x; 1.0296x over previous
//
#include <hip/hip_runtime.h>
#include <float.h>

// CropRoi, LDS-staged, 4 channels per block.
// Window bounds depend only on the proposal n (not channel), so each thread
// computes its (i,j,k) window math ONCE and keeps 4 independent channel
// maxes -> 4x ILP on the LDS-latency chain + 4x index-math amortization.
// Grid (C/4, N) = 1536 blocks x 256 threads; LDS 4*2744*4B = 43.9 KB
// -> 3 blocks / 12 waves per CU.

#define NTHREADS 256
#define NCH 4
#define MAXL 14
#define MAXV (MAXL * MAXL * MAXL)  // 2744

__global__ __launch_bounds__(NTHREADS) void crop_roi_lds4(
        const float* __restrict__ f,
        const float* __restrict__ props,
        float* __restrict__ out,
        int C) {
    __shared__ float s[NCH * MAXV];
    const int cbase = blockIdx.x * NCH;
    const int n = blockIdx.y;
    const int tid = threadIdx.x;

    const float* p = props + (size_t)n * 8;
    const int b = (int)p[0];

    // Bounds: float math matches JAX f32 exactly (exact *0.5, *0.25).
    int d0 = (int)floorf((p[2] - p[5] * 0.5f) * 0.25f);
    int d1 = (int)ceilf ((p[2] + p[5] * 0.5f) * 0.25f);
    int h0 = (int)floorf((p[3] - p[6] * 0.5f) * 0.25f);
    int h1 = (int)ceilf ((p[3] + p[6] * 0.5f) * 0.25f);
    int w0 = (int)floorf((p[4] - p[7] * 0.5f) * 0.25f);
    int w1 = (int)ceilf ((p[4] + p[7] * 0.5f) * 0.25f);
    d0 = max(d0, 0); d1 = min(d1, 32);
    h0 = max(h0, 0); h1 = min(h1, 32);
    w0 = max(w0, 0); w1 = min(w1, 32);
    const int Ld = d1 - d0, Lh = h1 - h0, Lw = w1 - w0;

    const float* base0 = f + (((size_t)b * C + cbase) << 15);  // 32^3
    const int nch = min(NCH, C - cbase);

    if (Ld <= MAXL && Lh <= MAXL && Lw <= MAXL) {
        const int D1 = Lh * Lw;   // <= 196
        const int V  = Ld * D1;   // <= 2744
        // magic reciprocals: exact floor-div for e <= 4096 (M = 2^32/D + 1)
        const unsigned Mdh = (D1 > 1) ? (unsigned)(0x100000000ULL / (unsigned)D1) + 1u : 0u;
        const unsigned Mw  = (Lw > 1) ? (unsigned)(0x100000000ULL / (unsigned)Lw) + 1u : 0u;

        // Phase 1: coalesced linear staging, per channel.
        for (int cs = 0; cs < nch; ++cs) {
            const float* basec = base0 + ((size_t)cs << 15);
            float* sc = s + cs * MAXV;
            for (int e = tid; e < V; e += NTHREADS) {
                unsigned d = (D1 > 1) ? __umulhi((unsigned)e, Mdh) : (unsigned)e;
                unsigned r = (unsigned)e - d * (unsigned)D1;
                unsigned h = (Lw > 1) ? __umulhi(r, Mw) : r;
                unsigned w = r - h * (unsigned)Lw;
                sc[e] = basec[((((d0 + (int)d) << 5) + (h0 + (int)h)) << 5) + w0 + (int)w];
            }
        }
        __syncthreads();

        // Phase 2: one (i,j,k) per thread iteration; 4 channels in flight.
        for (int o = tid; o < 343; o += NTHREADS) {
            const int i = o / 49;
            const int j = (o / 7) % 7;
            const int k = o % 7;
            const int a0 = (i * Ld) / 7,  a1 = ((i + 1) * Ld + 6) / 7;
            const int b0 = (j * Lh) / 7,  b1 = ((j + 1) * Lh + 6) / 7;
            const int g0 = (k * Lw) / 7,  g1 = ((k + 1) * Lw + 6) / 7;
            float m[NCH];
#pragma unroll
            for (int cs = 0; cs < NCH; ++cs) m[cs] = -FLT_MAX;
            for (int d = a0; d < a1; ++d) {
                for (int h = b0; h < b1; ++h) {
                    const int rowb = (d * Lh + h) * Lw;
                    for (int w = g0; w < g1; ++w) {
                        const int idx = rowb + w;
#pragma unroll
                        for (int cs = 0; cs < NCH; ++cs)
                            m[cs] = fmaxf(m[cs], s[cs * MAXV + idx]);
                    }
                }
            }
            for (int cs = 0; cs < nch; ++cs)
                out[((size_t)n * C + cbase + cs) * 343 + o] = m[cs];
        }
    } else {
        // Robust fallback (not taken for harness inputs): direct from global.
        for (int o = tid; o < 343; o += NTHREADS) {
            const int i = o / 49, j = (o / 7) % 7, k = o % 7;
            const int ds = d0 + (i * Ld) / 7, de = d0 + ((i + 1) * Ld + 6) / 7;
            const int hs = h0 + (j * Lh) / 7, he = h0 + ((j + 1) * Lh + 6) / 7;
            const int ws = w0 + (k * Lw) / 7, we = w0 + ((k + 1) * Lw + 6) / 7;
            for (int cs = 0; cs < nch; ++cs) {
                float m = -FLT_MAX;
                const float* basec = base0 + ((size_t)cs << 15);
                for (int d = ds; d < de; ++d)
                    for (int h = hs; h < he; ++h) {
                        const float* row = basec + (d << 10) + (h << 5);
                        for (int w = ws; w < we; ++w) m = fmaxf(m, row[w]);
                    }
                out[((size_t)n * C + cbase + cs) * 343 + o] = m;
            }
        }
    }
}

extern "C" void kernel_launch(void* const* d_in, const int* in_sizes, int n_in,
                              void* d_out, int out_size, void* d_ws, size_t ws_size,
                              hipStream_t stream) {
    const float* f = (const float*)d_in[0];
    const float* props = (const float*)d_in[2];

    int N = in_sizes[2] / 8;       // proposals are (N, 8)
    int C = out_size / (N * 343);  // outputs are (N, C, 7, 7, 7)

    dim3 block(NTHREADS);
    dim3 grid((C + NCH - 1) / NCH, N);
    crop_roi_lds4<<<grid, block, 0, stream>>>(f, props, (float*)d_out, C);
}

// Round 5
// 106.291 us; speedup vs baseline: 1.2692x; 1.0667x over previous
//
#include <hip/hip_runtime.h>
#include <float.h>

// CropRoi, LDS-staged, 4 channels per block, register-batched staging.
//
// Key fix vs R3: the staging loop had a dynamic trip count -> compiler
// emitted load/waitcnt/ds_write per element -> MLP ~ 1 -> latency-bound
// (~900 cyc/elem with caches flushed by the harness between replays).
// Now each unrolled body computes 8 clamped indices, issues 8x4 = 32
// independent global loads into registers, then 32 ds_writes. MLP ~ 32.
//
// Grid (C/4, N) x 256 threads; LDS 4*2744*4B = 43.9 KB -> 3 blocks/CU.

#define NTHREADS 256
#define NCH 4
#define MAXL 14
#define MAXV (MAXL * MAXL * MAXL)  // 2744
#define BATCH 8

__global__ __launch_bounds__(NTHREADS) void crop_roi_v4(
        const float* __restrict__ f,
        const float* __restrict__ props,
        float* __restrict__ out,
        int C) {
    __shared__ float s[NCH * MAXV];
    const int cbase = blockIdx.x * NCH;
    const int n = blockIdx.y;
    const int tid = threadIdx.x;

    const float* p = props + (size_t)n * 8;
    const int b = (int)p[0];

    // Bounds: float math matches JAX f32 exactly (exact *0.5, *0.25).
    int d0 = (int)floorf((p[2] - p[5] * 0.5f) * 0.25f);
    int d1 = (int)ceilf ((p[2] + p[5] * 0.5f) * 0.25f);
    int h0 = (int)floorf((p[3] - p[6] * 0.5f) * 0.25f);
    int h1 = (int)ceilf ((p[3] + p[6] * 0.5f) * 0.25f);
    int w0 = (int)floorf((p[4] - p[7] * 0.5f) * 0.25f);
    int w1 = (int)ceilf ((p[4] + p[7] * 0.5f) * 0.25f);
    d0 = max(d0, 0); d1 = min(d1, 32);
    h0 = max(h0, 0); h1 = min(h1, 32);
    w0 = max(w0, 0); w1 = min(w1, 32);
    const int Ld = d1 - d0, Lh = h1 - h0, Lw = w1 - w0;

    const float* base0 = f + (((size_t)b * C + cbase) << 15);  // 32^3
    const int nch = min(NCH, C - cbase);

    // channel offsets, clamped so loads never run past f for partial groups
    size_t choff[NCH];
#pragma unroll
    for (int cs = 0; cs < NCH; ++cs)
        choff[cs] = (size_t)min(cs, nch - 1) << 15;

    if (Ld <= MAXL && Lh <= MAXL && Lw <= MAXL) {
        const int D1 = Lh * Lw;   // <= 196
        const int V  = Ld * D1;   // <= 2744  (block-uniform)
        // magic reciprocals: exact floor-div for e <= 4096 (M = 2^32/D + 1)
        const unsigned Mdh = (D1 > 1) ? (unsigned)(0x100000000ULL / (unsigned)D1) + 1u : 0u;
        const unsigned Mw  = (Lw > 1) ? (unsigned)(0x100000000ULL / (unsigned)Lw) + 1u : 0u;

        // Phase 1: register-batched staging, 32 loads in flight.
        for (int e0 = tid; e0 < V; e0 += NTHREADS * BATCH) {
            int ec[BATCH], g[BATCH];
#pragma unroll
            for (int u = 0; u < BATCH; ++u) {
                int e = e0 + u * NTHREADS;
                e = min(e, V - 1);          // clamp: duplicate work is benign
                ec[u] = e;
                unsigned d = (D1 > 1) ? __umulhi((unsigned)e, Mdh) : (unsigned)e;
                unsigned r = (unsigned)e - d * (unsigned)D1;
                unsigned h = (Lw > 1) ? __umulhi(r, Mw) : r;
                unsigned w = r - h * (unsigned)Lw;
                g[u] = ((((d0 + (int)d) << 5) + (h0 + (int)h)) << 5) + (w0 + (int)w);
            }
            float rv[BATCH][NCH];
#pragma unroll
            for (int u = 0; u < BATCH; ++u)
#pragma unroll
                for (int cs = 0; cs < NCH; ++cs)
                    rv[u][cs] = base0[choff[cs] + g[u]];
#pragma unroll
            for (int u = 0; u < BATCH; ++u)
#pragma unroll
                for (int cs = 0; cs < NCH; ++cs)
                    s[cs * MAXV + ec[u]] = rv[u][cs];
        }
        __syncthreads();

        // Phase 2: one (i,j,k) per thread iteration; 4 channels in flight.
        for (int o = tid; o < 343; o += NTHREADS) {
            const int i = o / 49;
            const int j = (o / 7) % 7;
            const int k = o % 7;
            const int a0 = (i * Ld) / 7,  a1 = ((i + 1) * Ld + 6) / 7;
            const int b0 = (j * Lh) / 7,  b1 = ((j + 1) * Lh + 6) / 7;
            const int g0 = (k * Lw) / 7,  g1 = ((k + 1) * Lw + 6) / 7;
            float m[NCH];
#pragma unroll
            for (int cs = 0; cs < NCH; ++cs) m[cs] = -FLT_MAX;
            for (int d = a0; d < a1; ++d) {
                for (int h = b0; h < b1; ++h) {
                    const int rowb = (d * Lh + h) * Lw;
                    for (int w = g0; w < g1; ++w) {
                        const int idx = rowb + w;
#pragma unroll
                        for (int cs = 0; cs < NCH; ++cs)
                            m[cs] = fmaxf(m[cs], s[cs * MAXV + idx]);
                    }
                }
            }
            for (int cs = 0; cs < nch; ++cs)
                out[((size_t)n * C + cbase + cs) * 343 + o] = m[cs];
        }
    } else {
        // Robust fallback (not taken for harness inputs): direct from global.
        for (int o = tid; o < 343; o += NTHREADS) {
            const int i = o / 49, j = (o / 7) % 7, k = o % 7;
            const int ds = d0 + (i * Ld) / 7, de = d0 + ((i + 1) * Ld + 6) / 7;
            const int hs = h0 + (j * Lh) / 7, he = h0 + ((j + 1) * Lh + 6) / 7;
            const int ws = w0 + (k * Lw) / 7, we = w0 + ((k + 1) * Lw + 6) / 7;
            for (int cs = 0; cs < nch; ++cs) {
                float m = -FLT_MAX;
                const float* basec = base0 + ((size_t)cs << 15);
                for (int d = ds; d < de; ++d)
                    for (int h = hs; h < he; ++h) {
                        const float* row = basec + (d << 10) + (h << 5);
                        for (int w = ws; w < we; ++w) m = fmaxf(m, row[w]);
                    }
                out[((size_t)n * C + cbase + cs) * 343 + o] = m;
            }
        }
    }
}

extern "C" void kernel_launch(void* const* d_in, const int* in_sizes, int n_in,
                              void* d_out, int out_size, void* d_ws, size_t ws_size,
                              hipStream_t stream) {
    const float* f = (const float*)d_in[0];
    const float* props = (const float*)d_in[2];

    int N = in_sizes[2] / 8;       // proposals are (N, 8)
    int C = out_size / (N * 343);  // outputs are (N, C, 7, 7, 7)

    dim3 block(NTHREADS);
    dim3 grid((C + NCH - 1) / NCH, N);
    crop_roi_v4<<<grid, block, 0, stream>>>(f, props, (float*)d_out, C);
}

// Round 6
// 105.592 us; speedup vs baseline: 1.2776x; 1.0066x over previous
//
#include <hip/hip_runtime.h>
#include <float.h>

// CropRoi, LDS-staged, 4 channels/block, float4-aligned staging.
//
// vs R4: staging loads were per-lane dwords (4 B) -> VMEM-issue/latency
// bound at ~450 GB/s effective. Now each crop row is expanded to 16B-aligned
// boundaries (wlo = w0 & ~3, whi = (w1+3) & ~3, both within the 32-float
// row) and staged as float4: 4x fewer VMEM instructions, 4x bytes per
// outstanding load, all 16B-aligned; LDS rows at padded stride Wp
// (multiple of 4 -> ds_write_b128). Phase 2: stride Wp + w-offset.
//
// Grid (C/4, N) x 256 threads; LDS 4*3136*4B = 50.2 KB -> 3 blocks/CU.

#define NTHREADS 256
#define NCH 4
#define MAXL 14
#define MAXP (MAXL * MAXL * 16)  // padded per-channel floats: 3136
#define BATCH 4

__global__ __launch_bounds__(NTHREADS) void crop_roi_v5(
        const float* __restrict__ f,
        const float* __restrict__ props,
        float* __restrict__ out,
        int C) {
    __shared__ float s[NCH * MAXP];  // 50.2 KB
    const int cbase = blockIdx.x * NCH;
    const int n = blockIdx.y;
    const int tid = threadIdx.x;

    const float* p = props + (size_t)n * 8;
    const int b = (int)p[0];

    // Bounds: float math matches JAX f32 exactly (exact *0.5, *0.25).
    int d0 = (int)floorf((p[2] - p[5] * 0.5f) * 0.25f);
    int d1 = (int)ceilf ((p[2] + p[5] * 0.5f) * 0.25f);
    int h0 = (int)floorf((p[3] - p[6] * 0.5f) * 0.25f);
    int h1 = (int)ceilf ((p[3] + p[6] * 0.5f) * 0.25f);
    int w0 = (int)floorf((p[4] - p[7] * 0.5f) * 0.25f);
    int w1 = (int)ceilf ((p[4] + p[7] * 0.5f) * 0.25f);
    d0 = max(d0, 0); d1 = min(d1, 32);
    h0 = max(h0, 0); h1 = min(h1, 32);
    w0 = max(w0, 0); w1 = min(w1, 32);
    const int Ld = d1 - d0, Lh = h1 - h0, Lw = w1 - w0;

    const float* base0 = f + (((size_t)b * C + cbase) << 15);  // 32^3
    const int nch = min(NCH, C - cbase);

    size_t choff[NCH];
#pragma unroll
    for (int cs = 0; cs < NCH; ++cs)
        choff[cs] = (size_t)min(cs, nch - 1) << 15;

    if (Ld >= 1 && Ld <= MAXL && Lh >= 1 && Lh <= MAXL && Lw >= 1 && Lw <= MAXL) {
        const int wlo = w0 & ~3;
        const int whi = (w1 + 3) & ~3;        // <= 32, stays in-row
        const int Wp  = whi - wlo;            // padded row, multiple of 4
        const int Wp4 = Wp >> 2;              // float4s per row, 1..4
        const int woff = w0 - wlo;            // 0..3
        const int D1_4 = Lh * Wp4;            // float4s per d-slab, <= 56
        const int V4   = Ld * D1_4;           // float4s per channel, <= 784
        // magic reciprocals: exact floor-div for e < 2^12 (M = 2^32/D + 1)
        const unsigned Mdh = (D1_4 > 1) ? (unsigned)(0x100000000ULL / (unsigned)D1_4) + 1u : 0u;
        const unsigned Mw  = (Wp4  > 1) ? (unsigned)(0x100000000ULL / (unsigned)Wp4)  + 1u : 0u;

        // Phase 1: float4 staging, 16 float4 loads (256 B) in flight/lane.
        for (int e0 = tid; e0 < V4; e0 += NTHREADS * BATCH) {
            int ec[BATCH], g[BATCH];
#pragma unroll
            for (int u = 0; u < BATCH; ++u) {
                int e = min(e0 + u * NTHREADS, V4 - 1);  // clamp: dup benign
                unsigned d = (D1_4 > 1) ? __umulhi((unsigned)e, Mdh) : (unsigned)e;
                unsigned r = (unsigned)e - d * (unsigned)D1_4;
                unsigned h = (Wp4 > 1) ? __umulhi(r, Mw) : r;
                unsigned w4 = r - h * (unsigned)Wp4;
                ec[u] = (d * Lh + h) * Wp + (int)(w4 << 2);            // LDS float idx
                g[u]  = ((((d0 + (int)d) << 5) + (h0 + (int)h)) << 5)  // global float idx
                        + wlo + (int)(w4 << 2);
            }
            float4 rv[BATCH][NCH];
#pragma unroll
            for (int u = 0; u < BATCH; ++u)
#pragma unroll
                for (int cs = 0; cs < NCH; ++cs)
                    rv[u][cs] = *(const float4*)(base0 + choff[cs] + g[u]);
#pragma unroll
            for (int u = 0; u < BATCH; ++u)
#pragma unroll
                for (int cs = 0; cs < NCH; ++cs)
                    *(float4*)(s + cs * MAXP + ec[u]) = rv[u][cs];
        }
        __syncthreads();

        // Phase 2: one (i,j,k) per thread iteration; 4 channels in flight.
        for (int o = tid; o < 343; o += NTHREADS) {
            const int i = o / 49;
            const int j = (o / 7) % 7;
            const int k = o % 7;
            const int a0 = (i * Ld) / 7,  a1 = ((i + 1) * Ld + 6) / 7;
            const int b0 = (j * Lh) / 7,  b1 = ((j + 1) * Lh + 6) / 7;
            const int g0 = (k * Lw) / 7,  g1 = ((k + 1) * Lw + 6) / 7;
            float m[NCH];
#pragma unroll
            for (int cs = 0; cs < NCH; ++cs) m[cs] = -FLT_MAX;
            for (int d = a0; d < a1; ++d) {
                for (int h = b0; h < b1; ++h) {
                    const int rowb = (d * Lh + h) * Wp + woff;
                    for (int w = g0; w < g1; ++w) {
                        const int idx = rowb + w;
#pragma unroll
                        for (int cs = 0; cs < NCH; ++cs)
                            m[cs] = fmaxf(m[cs], s[cs * MAXP + idx]);
                    }
                }
            }
            for (int cs = 0; cs < nch; ++cs)
                out[((size_t)n * C + cbase + cs) * 343 + o] = m[cs];
        }
    } else {
        // Robust fallback (not taken for harness inputs): direct from global.
        for (int o = tid; o < 343; o += NTHREADS) {
            const int i = o / 49, j = (o / 7) % 7, k = o % 7;
            const int ds = d0 + (i * Ld) / 7, de = d0 + ((i + 1) * Ld + 6) / 7;
            const int hs = h0 + (j * Lh) / 7, he = h0 + ((j + 1) * Lh + 6) / 7;
            const int ws = w0 + (k * Lw) / 7, we = w0 + ((k + 1) * Lw + 6) / 7;
            for (int cs = 0; cs < nch; ++cs) {
                float m = -FLT_MAX;
                const float* basec = base0 + ((size_t)cs << 15);
                for (int d = ds; d < de; ++d)
                    for (int h = hs; h < he; ++h) {
                        const float* row = basec + (d << 10) + (h << 5);
                        for (int w = ws; w < we; ++w) m = fmaxf(m, row[w]);
                    }
                out[((size_t)n * C + cbase + cs) * 343 + o] = m;
            }
        }
    }
}

extern "C" void kernel_launch(void* const* d_in, const int* in_sizes, int n_in,
                              void* d_out, int out_size, void* d_ws, size_t ws_size,
                              hipStream_t stream) {
    const float* f = (const float*)d_in[0];
    const float* props = (const float*)d_in[2];

    int N = in_sizes[2] / 8;       // proposals are (N, 8)
    int C = out_size / (N * 343);  // outputs are (N, C, 7, 7, 7)

    dim3 block(NTHREADS);
    dim3 grid((C + NCH - 1) / NCH, N);
    crop_roi_v5<<<grid, block, 0, stream>>>(f, props, (float*)d_out, C);
}

// Round 8
// 102.764 us; speedup vs baseline: 1.3128x; 1.0275x over previous
//
#include <hip/hip_runtime.h>
#include <float.h>

// CropRoi, LDS-staged, 4 channels/block, fully-unrolled 3x3x3 phase 2.
//
// Domain: sides in [8,48] => crop length L <= 13 per axis. Adaptive segment
// i spans [floor(i*L/7), ceil((i+1)*L/7)): length 1..3 (3 occurs for L>=8 —
// R6's 2-element assumption was wrong). Elements {a0, min(a0+1,a1-1), a1-1}
// cover all cases; duplicate reads are idempotent under max. Phase 2 is 27
// independent ds_reads x 4 channels, branch-free, divergence-free.
//
// MAXL=13 -> LDS 4*2197*4B = 35.2 KB -> 4 blocks/CU (16 waves).
// Phase 1: guarded 9-deep batched dword staging (single pass, 9*256 >= 2197).

#define NTHREADS 256
#define NCH 4
#define MAXL 13
#define MAXV (MAXL * MAXL * MAXL)  // 2197
#define BATCH 9

__global__ __launch_bounds__(NTHREADS, 4) void crop_roi_v7(
        const float* __restrict__ f,
        const float* __restrict__ props,
        float* __restrict__ out,
        int C) {
    __shared__ float s[NCH * MAXV];  // 35.2 KB
    const int cbase = blockIdx.x * NCH;
    const int n = blockIdx.y;
    const int tid = threadIdx.x;

    const float* p = props + (size_t)n * 8;
    const int b = (int)p[0];

    // Bounds: float math matches JAX f32 exactly (exact *0.5, *0.25).
    int d0 = (int)floorf((p[2] - p[5] * 0.5f) * 0.25f);
    int d1 = (int)ceilf ((p[2] + p[5] * 0.5f) * 0.25f);
    int h0 = (int)floorf((p[3] - p[6] * 0.5f) * 0.25f);
    int h1 = (int)ceilf ((p[3] + p[6] * 0.5f) * 0.25f);
    int w0 = (int)floorf((p[4] - p[7] * 0.5f) * 0.25f);
    int w1 = (int)ceilf ((p[4] + p[7] * 0.5f) * 0.25f);
    d0 = max(d0, 0); d1 = min(d1, 32);
    h0 = max(h0, 0); h1 = min(h1, 32);
    w0 = max(w0, 0); w1 = min(w1, 32);
    const int Ld = d1 - d0, Lh = h1 - h0, Lw = w1 - w0;

    const float* base0 = f + (((size_t)b * C + cbase) << 15);  // 32^3
    const int nch = min(NCH, C - cbase);

    size_t choff[NCH];
#pragma unroll
    for (int cs = 0; cs < NCH; ++cs)
        choff[cs] = (size_t)min(cs, nch - 1) << 15;

    if (Ld >= 1 && Ld <= MAXL && Lh >= 1 && Lh <= MAXL && Lw >= 1 && Lw <= MAXL) {
        const int D1 = Lh * Lw;   // <= 169
        const int V  = Ld * D1;   // <= 2197 (block-uniform)
        // magic reciprocals: exact floor-div for e < 2^12 (M = 2^32/D + 1)
        const unsigned Mdh = (D1 > 1) ? (unsigned)(0x100000000ULL / (unsigned)D1) + 1u : 0u;
        const unsigned Mw  = (Lw > 1) ? (unsigned)(0x100000000ULL / (unsigned)Lw) + 1u : 0u;

        // Phase 1: guarded batched staging (single pass, BATCH*256 >= 2197).
        float rv[BATCH][NCH];
        int   ec[BATCH];
#pragma unroll
        for (int u = 0; u < BATCH; ++u) {
            const int e = tid + u * NTHREADS;
            if (e < V) {  // V block-uniform -> divergent only at boundary wave
                unsigned d = (D1 > 1) ? __umulhi((unsigned)e, Mdh) : (unsigned)e;
                unsigned r = (unsigned)e - d * (unsigned)D1;
                unsigned h = (Lw > 1) ? __umulhi(r, Mw) : r;
                unsigned w = r - h * (unsigned)Lw;
                const int g = ((((d0 + (int)d) << 5) + (h0 + (int)h)) << 5)
                              + w0 + (int)w;
                ec[u] = e;
#pragma unroll
                for (int cs = 0; cs < NCH; ++cs)
                    rv[u][cs] = base0[choff[cs] + g];
            }
        }
#pragma unroll
        for (int u = 0; u < BATCH; ++u) {
            if (tid + u * NTHREADS < V) {
#pragma unroll
                for (int cs = 0; cs < NCH; ++cs)
                    s[cs * MAXV + ec[u]] = rv[u][cs];
            }
        }
        __syncthreads();

        // Phase 2: 3x3x3 clamped window, fully unrolled, 4 channels.
        for (int o = tid; o < 343; o += NTHREADS) {
            const int i = o / 49;
            const int j = (o / 7) % 7;
            const int k = o % 7;
            const int a0 = (i * Ld) / 7,  a1 = ((i + 1) * Ld + 6) / 7;
            const int b0 = (j * Lh) / 7,  b1 = ((j + 1) * Lh + 6) / 7;
            const int g0 = (k * Lw) / 7,  g1 = ((k + 1) * Lw + 6) / 7;
            // segment elements: {a0, min(a0+1, a1-1), a1-1} (len 1..3)
            const int dd[3] = { a0, min(a0 + 1, a1 - 1), a1 - 1 };
            const int hh[3] = { b0, min(b0 + 1, b1 - 1), b1 - 1 };
            const int ww[3] = { g0, min(g0 + 1, g1 - 1), g1 - 1 };
            float m[NCH];
#pragma unroll
            for (int cs = 0; cs < NCH; ++cs) m[cs] = -FLT_MAX;
#pragma unroll
            for (int x = 0; x < 3; ++x) {
#pragma unroll
                for (int y = 0; y < 3; ++y) {
                    const int rowb = (dd[x] * Lh + hh[y]) * Lw;
#pragma unroll
                    for (int z = 0; z < 3; ++z) {
                        const int idx = rowb + ww[z];
#pragma unroll
                        for (int cs = 0; cs < NCH; ++cs)
                            m[cs] = fmaxf(m[cs], s[cs * MAXV + idx]);
                    }
                }
            }
            for (int cs = 0; cs < nch; ++cs)
                out[((size_t)n * C + cbase + cs) * 343 + o] = m[cs];
        }
    } else {
        // Robust fallback (not taken for harness inputs): direct from global.
        for (int o = tid; o < 343; o += NTHREADS) {
            const int i = o / 49, j = (o / 7) % 7, k = o % 7;
            const int ds = d0 + (i * Ld) / 7, de = d0 + ((i + 1) * Ld + 6) / 7;
            const int hs = h0 + (j * Lh) / 7, he = h0 + ((j + 1) * Lh + 6) / 7;
            const int ws = w0 + (k * Lw) / 7, we = w0 + ((k + 1) * Lw + 6) / 7;
            for (int cs = 0; cs < nch; ++cs) {
                float m = -FLT_MAX;
                const float* basec = base0 + ((size_t)cs << 15);
                for (int d = ds; d < de; ++d)
                    for (int h = hs; h < he; ++h) {
                        const float* row = basec + (d << 10) + (h << 5);
                        for (int w = ws; w < we; ++w) m = fmaxf(m, row[w]);
                    }
                out[((size_t)n * C + cbase + cs) * 343 + o] = m;
            }
        }
    }
}

extern "C" void kernel_launch(void* const* d_in, const int* in_sizes, int n_in,
                              void* d_out, int out_size, void* d_ws, size_t ws_size,
                              hipStream_t stream) {
    const float* f = (const float*)d_in[0];
    const float* props = (const float*)d_in[2];

    int N = in_sizes[2] / 8;       // proposals are (N, 8)
    int C = out_size / (N * 343);  // outputs are (N, C, 7, 7, 7)

    dim3 block(NTHREADS);
    dim3 grid((C + NCH - 1) / NCH, N);
    crop_roi_v7<<<grid, block, 0, stream>>>(f, props, (float*)d_out, C);
}

// Round 9
// 100.788 us; speedup vs baseline: 1.3385x; 1.0196x over previous
//
#include <hip/hip_runtime.h>
#include <float.h>

// CropRoi, LDS-staged, channel-interleaved float4 LDS, 3x3x3 phase 2.
//
// vs R7: the 4 channel values at each crop index are always consumed
// together, so LDS is laid out channel-interleaved: s4[idx] = {c0,c1,c2,c3}.
// Phase 2: 27 ds_read_b128 per output (was 108 ds_read_b32) -> 4x fewer
// LDS instructions. Phase 1: one ds_write_b128 per element (was 4 b32).
//
// Domain: sides in [8,48] => crop length L <= 13 => adaptive segment length
// 1..3; elements {a0, min(a0+1,a1-1), a1-1} cover all cases (duplicates
// idempotent under max). LDS 2197*16B = 35.2 KB -> 4 blocks/CU.

#define NTHREADS 256
#define NCH 4
#define MAXL 13
#define MAXV (MAXL * MAXL * MAXL)  // 2197
#define BATCH 9

__global__ __launch_bounds__(NTHREADS, 4) void crop_roi_v8(
        const float* __restrict__ f,
        const float* __restrict__ props,
        float* __restrict__ out,
        int C) {
    __shared__ float4 s4[MAXV];  // 35.2 KB, channel-interleaved
    const int cbase = blockIdx.x * NCH;
    const int n = blockIdx.y;
    const int tid = threadIdx.x;

    const float* p = props + (size_t)n * 8;
    const int b = (int)p[0];

    // Bounds: float math matches JAX f32 exactly (exact *0.5, *0.25).
    int d0 = (int)floorf((p[2] - p[5] * 0.5f) * 0.25f);
    int d1 = (int)ceilf ((p[2] + p[5] * 0.5f) * 0.25f);
    int h0 = (int)floorf((p[3] - p[6] * 0.5f) * 0.25f);
    int h1 = (int)ceilf ((p[3] + p[6] * 0.5f) * 0.25f);
    int w0 = (int)floorf((p[4] - p[7] * 0.5f) * 0.25f);
    int w1 = (int)ceilf ((p[4] + p[7] * 0.5f) * 0.25f);
    d0 = max(d0, 0); d1 = min(d1, 32);
    h0 = max(h0, 0); h1 = min(h1, 32);
    w0 = max(w0, 0); w1 = min(w1, 32);
    const int Ld = d1 - d0, Lh = h1 - h0, Lw = w1 - w0;

    const float* base0 = f + (((size_t)b * C + cbase) << 15);  // 32^3
    const int nch = min(NCH, C - cbase);

    size_t choff[NCH];
#pragma unroll
    for (int cs = 0; cs < NCH; ++cs)
        choff[cs] = (size_t)min(cs, nch - 1) << 15;

    if (Ld >= 1 && Ld <= MAXL && Lh >= 1 && Lh <= MAXL && Lw >= 1 && Lw <= MAXL) {
        const int D1 = Lh * Lw;   // <= 169
        const int V  = Ld * D1;   // <= 2197 (block-uniform)
        // magic reciprocals: exact floor-div for e < 2^12 (M = 2^32/D + 1)
        const unsigned Mdh = (D1 > 1) ? (unsigned)(0x100000000ULL / (unsigned)D1) + 1u : 0u;
        const unsigned Mw  = (Lw > 1) ? (unsigned)(0x100000000ULL / (unsigned)Lw) + 1u : 0u;

        // Phase 1: guarded batched staging (single pass, BATCH*256 >= 2197).
        float rv[BATCH][NCH];
        int   ec[BATCH];
#pragma unroll
        for (int u = 0; u < BATCH; ++u) {
            const int e = tid + u * NTHREADS;
            if (e < V) {  // V block-uniform -> divergent only at boundary wave
                unsigned d = (D1 > 1) ? __umulhi((unsigned)e, Mdh) : (unsigned)e;
                unsigned r = (unsigned)e - d * (unsigned)D1;
                unsigned h = (Lw > 1) ? __umulhi(r, Mw) : r;
                unsigned w = r - h * (unsigned)Lw;
                const int g = ((((d0 + (int)d) << 5) + (h0 + (int)h)) << 5)
                              + w0 + (int)w;
                ec[u] = e;
#pragma unroll
                for (int cs = 0; cs < NCH; ++cs)
                    rv[u][cs] = base0[choff[cs] + g];
            }
        }
#pragma unroll
        for (int u = 0; u < BATCH; ++u) {
            if (tid + u * NTHREADS < V) {
                s4[ec[u]] = make_float4(rv[u][0], rv[u][1], rv[u][2], rv[u][3]);
            }
        }
        __syncthreads();

        // Phase 2: 3x3x3 clamped window, one ds_read_b128 per index.
        for (int o = tid; o < 343; o += NTHREADS) {
            const int i = o / 49;
            const int j = (o / 7) % 7;
            const int k = o % 7;
            const int a0 = (i * Ld) / 7,  a1 = ((i + 1) * Ld + 6) / 7;
            const int b0 = (j * Lh) / 7,  b1 = ((j + 1) * Lh + 6) / 7;
            const int g0 = (k * Lw) / 7,  g1 = ((k + 1) * Lw + 6) / 7;
            // segment elements: {a0, min(a0+1, a1-1), a1-1} (len 1..3)
            const int dd[3] = { a0, min(a0 + 1, a1 - 1), a1 - 1 };
            const int hh[3] = { b0, min(b0 + 1, b1 - 1), b1 - 1 };
            const int ww[3] = { g0, min(g0 + 1, g1 - 1), g1 - 1 };
            float m0 = -FLT_MAX, m1 = -FLT_MAX, m2 = -FLT_MAX, m3 = -FLT_MAX;
#pragma unroll
            for (int x = 0; x < 3; ++x) {
#pragma unroll
                for (int y = 0; y < 3; ++y) {
                    const int rowb = (dd[x] * Lh + hh[y]) * Lw;
#pragma unroll
                    for (int z = 0; z < 3; ++z) {
                        const float4 v = s4[rowb + ww[z]];
                        m0 = fmaxf(m0, v.x);
                        m1 = fmaxf(m1, v.y);
                        m2 = fmaxf(m2, v.z);
                        m3 = fmaxf(m3, v.w);
                    }
                }
            }
            const float mm[NCH] = { m0, m1, m2, m3 };
            for (int cs = 0; cs < nch; ++cs)
                out[((size_t)n * C + cbase + cs) * 343 + o] = mm[cs];
        }
    } else {
        // Robust fallback (not taken for harness inputs): direct from global.
        for (int o = tid; o < 343; o += NTHREADS) {
            const int i = o / 49, j = (o / 7) % 7, k = o % 7;
            const int ds = d0 + (i * Ld) / 7, de = d0 + ((i + 1) * Ld + 6) / 7;
            const int hs = h0 + (j * Lh) / 7, he = h0 + ((j + 1) * Lh + 6) / 7;
            const int ws = w0 + (k * Lw) / 7, we = w0 + ((k + 1) * Lw + 6) / 7;
            for (int cs = 0; cs < nch; ++cs) {
                float m = -FLT_MAX;
                const float* basec = base0 + ((size_t)cs << 15);
                for (int d = ds; d < de; ++d)
                    for (int h = hs; h < he; ++h) {
                        const float* row = basec + (d << 10) + (h << 5);
                        for (int w = ws; w < we; ++w) m = fmaxf(m, row[w]);
                    }
                out[((size_t)n * C + cbase + cs) * 343 + o] = m;
            }
        }
    }
}

extern "C" void kernel_launch(void* const* d_in, const int* in_sizes, int n_in,
                              void* d_out, int out_size, void* d_ws, size_t ws_size,
                              hipStream_t stream) {
    const float* f = (const float*)d_in[0];
    const float* props = (const float*)d_in[2];

    int N = in_sizes[2] / 8;       // proposals are (N, 8)
    int C = out_size / (N * 343);  // outputs are (N, C, 7, 7, 7)

    dim3 block(NTHREADS);
    dim3 grid((C + NCH - 1) / NCH, N);
    crop_roi_v8<<<grid, block, 0, stream>>>(f, props, (float*)d_out, C);
}